// Round 2
// baseline (291.276 us; speedup 1.0000x reference)
//
#include <hip/hip_runtime.h>

// hd_id_lvl_decoder: scores[b,i,l] = sum_d x[b,d]*id[i,d]*lvl[l,d]; out[b,i] = argmax_l * 0.015625
// B=64, NUM_ID=256, NUM_LVL=64, D=10000. fp32 vector ALU (no fp32 MFMA on CDNA4).
//
// Phase 1: K-split GEMM-like kernel. Block tile = 64 i x 64 l x 8 b, thread tile = 8x4x4 (128 acc).
//          Grid = 32 * S blocks (S = K-splits, runtime from ws_size; S=16 -> 512 blocks = 2/CU).
// Phase 2: per (b,i): sum S partials in fp64, argmax over 64 l (first-index ties).

constexpr int D  = 10000;
constexpr int B  = 64;
constexpr int NI = 256;
constexpr int NL = 64;
constexpr int KC = 20;                 // k per chunk
constexpr int TOTAL_CH = D / KC;       // 500 chunks total
constexpr float BIN_LEN = 0.015625f;

constexpr int TI = 64;                 // i per block
constexpr int TB = 8;                  // b per block
constexpr int UNITS = (64 + 64 + 8) * (KC / 4);  // 680 float4 staging units per chunk

__device__ __forceinline__ float4 ld4(const float* p) {
    return *reinterpret_cast<const float4*>(p);
}

struct Pre { float4 v[3]; };

__device__ __forceinline__ void stage_load(Pre& r, const float* __restrict__ id_hvs,
                                           const float* __restrict__ lvl_hvs,
                                           const float* __restrict__ x,
                                           int kk, int ibase, int bbase, int tid) {
#pragma unroll
    for (int m = 0; m < 3; ++m) {
        int u = tid + 256 * m;
        if (u < UNITS) {
            const float* src;
            if (u < 320) {                   // id tile: 64 cols x 5 kgroups
                int col = u & 63, g = u >> 6;
                src = id_hvs + (size_t)(ibase + col) * D + kk + 4 * g;
            } else if (u < 640) {            // lvl tile
                int u2 = u - 320;
                int col = u2 & 63, g = u2 >> 6;
                src = lvl_hvs + (size_t)col * D + kk + 4 * g;
            } else {                         // x tile: 8 cols x 5 kgroups
                int u3 = u - 640;
                int col = u3 & 7, g = u3 >> 3;
                src = x + (size_t)(bbase + col) * D + kk + 4 * g;
            }
            r.v[m] = ld4(src);
        }
    }
}

__device__ __forceinline__ void stage_write(float (*pid)[64], float (*plvl)[64],
                                            float (*px)[8], const Pre& r, int tid) {
#pragma unroll
    for (int m = 0; m < 3; ++m) {
        int u = tid + 256 * m;
        if (u < UNITS) {
            float vv[4] = {r.v[m].x, r.v[m].y, r.v[m].z, r.v[m].w};
            if (u < 320) {
                int col = u & 63, g = u >> 6;
#pragma unroll
                for (int j = 0; j < 4; ++j) pid[4 * g + j][col] = vv[j];
            } else if (u < 640) {
                int u2 = u - 320;
                int col = u2 & 63, g = u2 >> 6;
#pragma unroll
                for (int j = 0; j < 4; ++j) plvl[4 * g + j][col] = vv[j];
            } else {
                int u3 = u - 640;
                int col = u3 & 7, g = u3 >> 3;
#pragma unroll
                for (int j = 0; j < 4; ++j) px[4 * g + j][col] = vv[j];
            }
        }
    }
}

__global__ __launch_bounds__(256, 2)
void hd_phase1(const float* __restrict__ x, const float* __restrict__ id_hvs,
               const float* __restrict__ lvl_hvs, float* __restrict__ ws, int S) {
    __shared__ float sid[2][KC][64];
    __shared__ float slvl[2][KC][64];
    __shared__ float sx[2][KC][8];

    const int tid = threadIdx.x;
    const int bx  = blockIdx.x;
    const int s    = bx >> 5;         // split index (32 blocks per split)
    const int bblk = (bx >> 2) & 7;   // 8 b-blocks
    const int iblk = bx & 3;          // 4 i-blocks
    const int ibase = iblk * TI;
    const int bbase = bblk * TB;

    const int lcol = (tid & 15) * 4;        // Q=4 l's
    const int icol = ((tid >> 4) & 7) * 8;  // P=8 i's
    const int bcol = (tid >> 7) * 4;        // R=4 b's

    // split k-range (all multiples of KC -> 16B-aligned global float4 loads)
    const int cbase = TOTAL_CH / S, crem = TOTAL_CH % S;
    const int cstart = s * cbase + (s < crem ? s : crem);
    const int nch    = cbase + (s < crem ? 1 : 0);
    const int k0     = cstart * KC;

    float acc[4][8][4];  // [r=b][p=i][q=l]
#pragma unroll
    for (int r = 0; r < 4; ++r)
#pragma unroll
        for (int p = 0; p < 8; ++p)
#pragma unroll
            for (int q = 0; q < 4; ++q) acc[r][p][q] = 0.0f;

    Pre pre;
    stage_load(pre, id_hvs, lvl_hvs, x, k0, ibase, bbase, tid);
    stage_write(sid[0], slvl[0], sx[0], pre, tid);
    __syncthreads();

    int cur = 0;
    for (int c = 0; c < nch; ++c) {
        const bool more = (c + 1 < nch);
        if (more) stage_load(pre, id_hvs, lvl_hvs, x, k0 + (c + 1) * KC, ibase, bbase, tid);

        const float (*pid)[64] = sid[cur];
        const float (*plvl)[64] = slvl[cur];
        const float (*px)[8] = sx[cur];

#pragma unroll 5
        for (int k = 0; k < KC; ++k) {
            const float4 A0 = ld4(&pid[k][icol]);
            const float4 A1 = ld4(&pid[k][icol + 4]);
            const float4 LV = ld4(&plvl[k][lcol]);
            const float4 XV = ld4(&px[k][bcol]);
            const float a[8]  = {A0.x, A0.y, A0.z, A0.w, A1.x, A1.y, A1.z, A1.w};
            const float lq[4] = {LV.x, LV.y, LV.z, LV.w};
            const float xr[4] = {XV.x, XV.y, XV.z, XV.w};
            float w[4][4];
#pragma unroll
            for (int r = 0; r < 4; ++r)
#pragma unroll
                for (int q = 0; q < 4; ++q) w[r][q] = xr[r] * lq[q];
#pragma unroll
            for (int r = 0; r < 4; ++r)
#pragma unroll
                for (int p = 0; p < 8; ++p)
#pragma unroll
                    for (int q = 0; q < 4; ++q)
                        acc[r][p][q] = fmaf(a[p], w[r][q], acc[r][p][q]);
        }

        if (more) stage_write(sid[cur ^ 1], slvl[cur ^ 1], sx[cur ^ 1], pre, tid);
        __syncthreads();
        cur ^= 1;
    }

    // store partials: ws[((s*64 + b)*256 + i)*64 + l]
#pragma unroll
    for (int r = 0; r < 4; ++r) {
#pragma unroll
        for (int p = 0; p < 8; ++p) {
            float4 o;
            o.x = acc[r][p][0]; o.y = acc[r][p][1]; o.z = acc[r][p][2]; o.w = acc[r][p][3];
            size_t idx = (((size_t)(s * B + bbase + bcol + r)) * NI + (ibase + icol + p)) * NL + lcol;
            *reinterpret_cast<float4*>(ws + idx) = o;
        }
    }
}

__global__ __launch_bounds__(256)
void hd_phase2(const float* __restrict__ ws, float* __restrict__ out, int S) {
    const int bi = blockIdx.x * 256 + threadIdx.x;  // 0..16383
    const int b = bi >> 8, i = bi & 255;
    const float* base = ws + ((size_t)b * NI + i) * NL;
    const size_t sstride = (size_t)B * NI * NL;     // 1,048,576

    double mv = -1e300;
    int mi = 0;
    for (int lg = 0; lg < 16; ++lg) {
        double sum[4] = {0.0, 0.0, 0.0, 0.0};
        for (int ss = 0; ss < S; ++ss) {
            float4 v = ld4(base + (size_t)ss * sstride + lg * 4);
            sum[0] += (double)v.x; sum[1] += (double)v.y;
            sum[2] += (double)v.z; sum[3] += (double)v.w;
        }
#pragma unroll
        for (int j = 0; j < 4; ++j) {
            if (sum[j] > mv) { mv = sum[j]; mi = lg * 4 + j; }  // strict > keeps first index
        }
    }
    out[bi] = (float)mi * BIN_LEN;
}

extern "C" void kernel_launch(void* const* d_in, const int* in_sizes, int n_in,
                              void* d_out, int out_size, void* d_ws, size_t ws_size,
                              hipStream_t stream) {
    const float* x       = (const float*)d_in[0];
    const float* id_hvs  = (const float*)d_in[1];
    const float* lvl_hvs = (const float*)d_in[2];
    float* out = (float*)d_out;
    float* ws  = (float*)d_ws;

    // pick largest split count whose partial buffer (S * 4 MiB) fits in ws
    int S = 16;
    while (S > 1 && ws_size < ((size_t)S << 22)) S >>= 1;

    hd_phase1<<<dim3(32 * S), dim3(256), 0, stream>>>(x, id_hvs, lvl_hvs, ws, S);
    hd_phase2<<<dim3(B * NI / 256), dim3(256), 0, stream>>>(ws, out, S);
}